// Round 6
// baseline (138.655 us; speedup 1.0000x reference)
//
#include <hip/hip_runtime.h>

// BCH truncated series on 3D periodic velocity fields — v5: v4 + NT stores.
// out_i = L_i + R_i + 0.25 * sum_j [ dL_i^j * R_j - dR_i^j * L_j ]
// (central differences, circulant bounds, channels-first (B,D,X,Y,Z)).
//
// v5 = v4 (measured 45.5 us/dispatch, VGPR=56, FETCH 62 MB, WRITE 49 MB)
// with EXACTLY ONE change: nontemporal float4 output stores. Output is
// write-once; streaming it past L2/L3 should let the 96 MB input stay
// L3-resident across dispatches (FETCH_SIZE was already < input size,
// proving partial retention). Prediction: FETCH_SIZE 62 -> 10-30 MB,
// dur 45.5 -> 33-40 us. If FETCH doesn't drop: theory wrong, revert NT.
//
// Kept from v4:
//  - One x-plane per block; x+-1 planes gathered (12 independent f4 loads)
//    issued up front with center loads: one latency window.
//  - y+-1 from LDS-staged center plane, halo rows in LDS.
//  - z+-1 via width-32 shuffles.
//  - grid = 4096; NO __launch_bounds__ min-waves pin (R2: spill disaster).

namespace {
constexpr int Xd = 128, Yd = 128, Zd = 128, Dd = 3;
constexpr int Sd  = Xd * Yd * Zd;   // channel stride
constexpr int YZd = Yd * Zd;        // x-plane stride
constexpr int YT  = 8;              // y rows per block
constexpr int ZC  = 32;             // float4 chunks per z-line

typedef float f32x4_t __attribute__((ext_vector_type(4)));

__device__ inline float4 f4sub(float4 a, float4 b) {
    return make_float4(a.x - b.x, a.y - b.y, a.z - b.z, a.w - b.w);
}
__device__ inline float4 f4add(float4 a, float4 b) {
    return make_float4(a.x + b.x, a.y + b.y, a.z + b.z, a.w + b.w);
}
__device__ inline float4 f4mul(float4 a, float4 b) {
    return make_float4(a.x * b.x, a.y * b.y, a.z * b.z, a.w * b.w);
}
__device__ inline float4 f4fma(float4 a, float4 b, float4 c) {
    return make_float4(fmaf(a.x, b.x, c.x), fmaf(a.y, b.y, c.y),
                       fmaf(a.z, b.z, c.z), fmaf(a.w, b.w, c.w));
}
// c - a*b
__device__ inline float4 f4fms(float4 a, float4 b, float4 c) {
    return make_float4(fmaf(-a.x, b.x, c.x), fmaf(-a.y, b.y, c.y),
                       fmaf(-a.z, b.z, c.z), fmaf(-a.w, b.w, c.w));
}
__device__ inline void store_nt(float* p, float4 v) {
    __builtin_nontemporal_store(*(const f32x4_t*)&v, (f32x4_t*)p);
}
} // namespace

__global__ void __launch_bounds__(256)
bch_plane(const float* __restrict__ L, const float* __restrict__ R,
          float* __restrict__ O)
{
    // [0..2]=L channels, [3..5]=R channels; rows 1..YT = center, 0 / YT+1 = halo
    __shared__ float4 sP[2 * Dd][YT + 2][ZC];   // 30 KB

    const int t  = threadIdx.x;
    const int zc = t & 31;          // z chunk (float4) within line
    const int ly = t >> 5;          // local y row 0..7

    int bb = blockIdx.x;            // grid = 16 * 128 * 2 = 4096
    const int yt = bb & 15; bb >>= 4;    // y tile (low bits: 16 consecutive
    const int x  = bb & 127; bb >>= 7;   //   blocks share one x-neighborhood)
    const int b  = bb;

    const int y  = yt * YT + ly;
    const int z0 = zc * 4;

    const int fbase = b * (Dd * Sd) + x * YZd + y * Zd + z0;
    const float* pL = L + fbase;
    const float* pR = R + fbase;
    float*       pO = O + fbase;

    const int oxp = (((x + 1) & 127) - x) * YZd;  // wrapped x+1 plane offset
    const int oxm = (((x - 1) & 127) - x) * YZd;  // wrapped x-1 plane offset
    const int oym = (((y - 1) & 127) - y) * Zd;   // wrapped y-1 row offset
    const int oyp = (((y + 1) & 127) - y) * Zd;   // wrapped y+1 row offset
    const int zlm = (zc + 31) & 31;   // shfl source lane for z-1 (.w)
    const int zlp = (zc + 1) & 31;    // shfl source lane for z+4 (.x)

    // ---- issue ALL global loads up front (one latency window) ----
    float4 BL[3], BR[3];              // center plane
    float4 XPL[3], XML[3], XPR[3], XMR[3];   // x+1 / x-1 gathers
#pragma unroll
    for (int d = 0; d < 3; ++d) {
        BL[d]  = *(const float4*)(pL + d * Sd);
        BR[d]  = *(const float4*)(pR + d * Sd);
        XPL[d] = *(const float4*)(pL + oxp + d * Sd);
        XML[d] = *(const float4*)(pL + oxm + d * Sd);
        XPR[d] = *(const float4*)(pR + oxp + d * Sd);
        XMR[d] = *(const float4*)(pR + oxm + d * Sd);
    }

    const bool lo = (ly == 0);
    const bool hi = (ly == YT - 1);
    if (lo | hi) {
        const int oyh  = lo ? oym : oyp;
        const int hrow = lo ? 0 : YT + 1;
        float4 H[6];
#pragma unroll
        for (int d = 0; d < 3; ++d) {
            H[d]     = *(const float4*)(pL + oyh + d * Sd);
            H[3 + d] = *(const float4*)(pR + oyh + d * Sd);
        }
#pragma unroll
        for (int d = 0; d < 6; ++d) sP[d][hrow][zc] = H[d];
    }

    // Stage center plane in LDS.
#pragma unroll
    for (int d = 0; d < 3; ++d) {
        sP[d][ly + 1][zc]     = BL[d];
        sP[3 + d][ly + 1][zc] = BR[d];
    }
    __syncthreads();

    // y-neighbors: uniform LDS reads (halo rows included in tile).
    float4 yLm[3], yRm[3], yLp[3], yRp[3];
#pragma unroll
    for (int d = 0; d < 3; ++d) {
        yLm[d] = sP[d][ly][zc];
        yLp[d] = sP[d][ly + 2][zc];
        yRm[d] = sP[3 + d][ly][zc];
        yRp[d] = sP[3 + d][ly + 2][zc];
    }

#pragma unroll
    for (int i = 0; i < 3; ++i) {
        // j = 0 (x): from gathered planes
        float4 dl = f4sub(XPL[i], XML[i]);
        float4 dr = f4sub(XPR[i], XMR[i]);
        float4 br = f4fms(dr, BL[0], f4mul(dl, BR[0]));

        // j = 1 (y): from LDS
        dl = f4sub(yLp[i], yLm[i]);
        dr = f4sub(yRp[i], yRm[i]);
        br = f4fms(dr, BL[1], f4fma(dl, BR[1], br));

        // j = 2 (z): shift-in-register + width-32 shuffles (wrap in line)
        const float lzm = __shfl(BL[i].w, zlm, 32);
        const float lzp = __shfl(BL[i].x, zlp, 32);
        const float rzm = __shfl(BR[i].w, zlm, 32);
        const float rzp = __shfl(BR[i].x, zlp, 32);
        dl = make_float4(BL[i].y - lzm, BL[i].z - BL[i].x,
                         BL[i].w - BL[i].y, lzp - BL[i].z);
        dr = make_float4(BR[i].y - rzm, BR[i].z - BR[i].x,
                         BR[i].w - BR[i].y, rzp - BR[i].z);
        br = f4fms(dr, BL[2], f4fma(dl, BR[2], br));

        float4 out = f4add(BL[i], BR[i]);
        const float4 q = make_float4(0.25f, 0.25f, 0.25f, 0.25f);
        out = f4fma(q, br, out);
        store_nt(pO + i * Sd, out);
    }
}

extern "C" void kernel_launch(void* const* d_in, const int* in_sizes, int n_in,
                              void* d_out, int out_size, void* d_ws, size_t ws_size,
                              hipStream_t stream)
{
    const float* L = (const float*)d_in[0];
    const float* R = (const float*)d_in[1];
    float*       O = (float*)d_out;

    const int nblocks = (Yd / YT) * Xd * 2;   // 4096
    bch_plane<<<dim3(nblocks), dim3(256), 0, stream>>>(L, R, O);
}